// Round 1
// baseline (425.640 us; speedup 1.0000x reference)
//
#include <hip/hip_runtime.h>
#include <math.h>

// Problem constants
constexpr int E = 8, H = 1024, DFF = 2048, T = 4096;
constexpr int TR = 8192;          // total routed rows = T * topk
constexpr int MAXJ2 = TR / 256 + E;   // 40: k2 jobs (256-row tiles)
constexpr int MAXJ3 = TR / 128 + E;   // 72: k3 jobs (128-row tiles)

typedef __bf16 bf16x8 __attribute__((ext_vector_type(8)));
typedef __bf16 bf16x4 __attribute__((ext_vector_type(4)));
typedef float f32x4 __attribute__((ext_vector_type(4)));

__device__ __forceinline__ void gload16(const void* g, void* l) {
    __builtin_amdgcn_global_load_lds(
        (const __attribute__((address_space(1))) unsigned int*)g,
        (__attribute__((address_space(3))) unsigned int*)l, 16, 0, 0);
}

// ---------------- k1: affinity + top-2 (atomic-free) ----------------
__global__ __launch_bounds__(256) void k1_affinity(
    const float* __restrict__ x, const float* __restrict__ cent,
    const float* __restrict__ bias,
    int* __restrict__ se, float* __restrict__ sw) {
    __shared__ float cs[E * H];
    int tid = threadIdx.x;
    for (int i = tid; i < E * H / 4; i += 256)
        ((float4*)cs)[i] = ((const float4*)cent)[i];
    __syncthreads();

    int wave = tid >> 6, lane = tid & 63;
    int t = blockIdx.x * 4 + wave;
    const float4* xr = (const float4*)(x + (size_t)t * H);
    float acc[E] = {};
    #pragma unroll
    for (int it = 0; it < 4; it++) {
        float4 xv = xr[lane + it * 64];
        #pragma unroll
        for (int e = 0; e < E; e++) {
            float4 cv = ((const float4*)(cs + e * H))[lane + it * 64];
            acc[e] = fmaf(xv.x, cv.x, acc[e]);
            acc[e] = fmaf(xv.y, cv.y, acc[e]);
            acc[e] = fmaf(xv.z, cv.z, acc[e]);
            acc[e] = fmaf(xv.w, cv.w, acc[e]);
        }
    }
    #pragma unroll
    for (int off = 32; off; off >>= 1)
        #pragma unroll
        for (int e = 0; e < E; e++) acc[e] += __shfl_down(acc[e], off);

    if (lane == 0) {
        float s[E];
        #pragma unroll
        for (int e = 0; e < E; e++)
            s[e] = 1.0f / (1.0f + expf(-acc[e])) + bias[e];
        int i0 = 0;
        for (int e = 1; e < E; e++) if (s[e] > s[i0]) i0 = e;
        int i1 = -1;
        for (int e = 0; e < E; e++) {
            if (e == i0) continue;
            if (i1 < 0 || s[e] > s[i1]) i1 = e;
        }
        float m = fmaxf(s[i0], s[i1]);
        float w0 = expf(s[i0] - m), w1 = expf(s[i1] - m);
        float inv = 1.0f / (w0 + w1);
        se[2 * t] = i0;     sw[2 * t] = w0 * inv;
        se[2 * t + 1] = i1; sw[2 * t + 1] = w1 * inv;
    }
}

// ---------------- k1b: per-expert partition via block scan ----------------
__global__ __launch_bounds__(256) void k1b_partition(
    const int* __restrict__ se, int* __restrict__ token_list,
    int* __restrict__ sp, int* __restrict__ cnt) {
    int e = blockIdx.x;
    int tid = threadIdx.x;
    int wave = tid >> 6, lane = tid & 63;
    __shared__ int wsum[4];
    int running = 0;
    for (int c0 = 0; c0 < 2 * T; c0 += 256) {
        int i = c0 + tid;
        bool pred = (se[i] == e);
        unsigned long long mask = __ballot(pred);
        int pos_in_wave = __popcll(mask & ((1ull << lane) - 1ull));
        if (lane == 0) wsum[wave] = __popcll(mask);
        __syncthreads();
        int wbase = 0;
        for (int w2 = 0; w2 < wave; w2++) wbase += wsum[w2];
        int total = wsum[0] + wsum[1] + wsum[2] + wsum[3];
        if (pred) {
            int p = running + wbase + pos_in_wave;
            token_list[e * T + p] = i >> 1;
            sp[i] = p;
        }
        running += total;
        __syncthreads();
    }
    if (tid == 0) cnt[e] = running;
}

// ---------------- k1.5: offsets + counts output + two job tables ----------------
__global__ void k15_offsets(const int* __restrict__ cnt, int* __restrict__ off,
                            float* __restrict__ out_counts,
                            int* __restrict__ jobs2, int* __restrict__ jobs3,
                            int* __restrict__ njobs) {
    if (threadIdx.x == 0) {
        int acc = 0, nj2 = 0, nj3 = 0;
        for (int e = 0; e < E; e++) {
            off[e] = acc; acc += cnt[e];
            int m2 = (cnt[e] + 255) >> 8;
            for (int mt = 0; mt < m2; mt++) jobs2[nj2++] = e * 64 + mt;
            int m3 = (cnt[e] + 127) >> 7;
            for (int mt = 0; mt < m3; mt++) jobs3[nj3++] = e * 64 + mt;
        }
        njobs[0] = nj2;
        njobs[1] = nj3;
    }
    if (threadIdx.x < E) out_counts[threadIdx.x] = (float)cnt[threadIdx.x];
}

// ---------------- conv: fp32 -> bf16 (single tensor) ----------------
__global__ __launch_bounds__(256) void k_conv(const float* __restrict__ in,
                                              __bf16* __restrict__ out, int n4) {
    int i = blockIdx.x * 256 + threadIdx.x;
    if (i < n4) {
        float4 v = ((const float4*)in)[i];
        bf16x4 o = {(__bf16)v.x, (__bf16)v.y, (__bf16)v.z, (__bf16)v.w};
        ((bf16x4*)out)[i] = o;
    }
}

// ---------------- conv3: gw, uw, x in one launch ----------------
__global__ __launch_bounds__(256) void k_conv3(
    const float* __restrict__ gw, __bf16* __restrict__ gwb,
    const float* __restrict__ uw, __bf16* __restrict__ uwb,
    const float* __restrict__ x, __bf16* __restrict__ xb,
    int w4, int x4) {
    int i = blockIdx.x * 256 + threadIdx.x;
    const float* in; __bf16* out; int idx;
    if (i < w4) { in = gw; out = gwb; idx = i; }
    else if (i < 2 * w4) { in = uw; out = uwb; idx = i - w4; }
    else { idx = i - 2 * w4; if (idx >= x4) return; in = x; out = xb; }
    float4 v = ((const float4*)in)[idx];
    bf16x4 o = {(__bf16)v.x, (__bf16)v.y, (__bf16)v.z, (__bf16)v.w};
    ((bf16x4*)out)[idx] = o;
}

// ---------------- k2: grouped GEMM gate+up (MFMA), tile 256x128 dual ----------------
// 512 threads, 8 waves (4m x 2n); each wave owns a 64x64 region of BOTH
// gate and up accumulators. Double-buffered LDS (128 KiB), prefetch-2-phase:
// issue STAGE(next) -> compute(cur) -> vmcnt(0)+barrier (one per K-step).
__global__ __launch_bounds__(512, 2) void k2_gateup(
    const __bf16* __restrict__ xb, const __bf16* __restrict__ gwb,
    const __bf16* __restrict__ uwb, const int* __restrict__ cnt,
    const int* __restrict__ off, const int* __restrict__ token_list,
    const int* __restrict__ jobs, const int* __restrict__ njobs,
    __bf16* __restrict__ h) {
    int jt = blockIdx.x >> 4, nt = blockIdx.x & 15;   // nt: 0..15 (DFF/128)
    if (jt >= njobs[0]) return;
    int job = jobs[jt];
    int e = job >> 6, mt = job & 63;
    int Me = cnt[e], offe = off[e];

    __shared__ __bf16 As[2][256 * 64];   // 64 KB
    __shared__ __bf16 Bg[2][128 * 64];   // 32 KB
    __shared__ __bf16 Bu[2][128 * 64];   // 32 KB

    int tid = threadIdx.x;
    int lane = tid & 63, w = tid >> 6;
    int wm = w >> 1, wn = w & 1;          // 4m x 2n waves

    // staging sources: LDS slot (row, l&7) receives global k-chunk (l&7)^(row&7)
    const __bf16* asrc[4];
    const __bf16 *bsg[2], *bsu[2];
    #pragma unroll
    for (int rr = 0; rr < 4; rr++) {
        int l = rr * 512 + tid;
        int row = l >> 3, sl = l & 7;
        int gr = mt * 256 + row; if (gr >= Me) gr = Me - 1;
        int tok = token_list[e * T + gr];
        asrc[rr] = xb + (size_t)tok * H + ((sl ^ (row & 7)) * 8);
    }
    #pragma unroll
    for (int rr = 0; rr < 2; rr++) {
        int l = rr * 512 + tid;
        int row = l >> 3, sl = l & 7;
        size_t base = ((size_t)e * DFF + nt * 128 + row) * H + ((sl ^ (row & 7)) * 8);
        bsg[rr] = gwb + base;
        bsu[rr] = uwb + base;
    }

    f32x4 accg[4][4] = {};
    f32x4 accu[4][4] = {};
    int kq = lane >> 4, m15 = lane & 15;

    // prologue: stage k-tile 0 into buffer 0
    #pragma unroll
    for (int rr = 0; rr < 4; rr++) gload16(asrc[rr], &As[0][(rr * 512 + tid) * 8]);
    #pragma unroll
    for (int rr = 0; rr < 2; rr++) gload16(bsg[rr], &Bg[0][(rr * 512 + tid) * 8]);
    #pragma unroll
    for (int rr = 0; rr < 2; rr++) gload16(bsu[rr], &Bu[0][(rr * 512 + tid) * 8]);
    __syncthreads();

    int cur = 0;
    for (int k0 = 0; k0 < H; k0 += 64) {
        // prefetch next K-tile into the other buffer BEFORE compute
        if (k0 + 64 < H) {
            int nb = cur ^ 1, kn = k0 + 64;
            #pragma unroll
            for (int rr = 0; rr < 4; rr++) gload16(asrc[rr] + kn, &As[nb][(rr * 512 + tid) * 8]);
            #pragma unroll
            for (int rr = 0; rr < 2; rr++) gload16(bsg[rr] + kn, &Bg[nb][(rr * 512 + tid) * 8]);
            #pragma unroll
            for (int rr = 0; rr < 2; rr++) gload16(bsu[rr] + kn, &Bu[nb][(rr * 512 + tid) * 8]);
        }

        #pragma unroll
        for (int kc = 0; kc < 2; kc++) {
            bf16x8 af[4], gf[4], uf[4];
            #pragma unroll
            for (int i = 0; i < 4; i++) {
                int row = wm * 64 + i * 16 + m15;
                int sl = (kc * 4 + kq) ^ (row & 7);
                af[i] = *(const bf16x8*)&As[cur][row * 64 + sl * 8];
            }
            #pragma unroll
            for (int j = 0; j < 4; j++) {
                int row = wn * 64 + j * 16 + m15;
                int sl = (kc * 4 + kq) ^ (row & 7);
                gf[j] = *(const bf16x8*)&Bg[cur][row * 64 + sl * 8];
                uf[j] = *(const bf16x8*)&Bu[cur][row * 64 + sl * 8];
            }
            #pragma unroll
            for (int i = 0; i < 4; i++)
                #pragma unroll
                for (int j = 0; j < 4; j++) {
                    accg[i][j] = __builtin_amdgcn_mfma_f32_16x16x32_bf16(af[i], gf[j], accg[i][j], 0, 0, 0);
                    accu[i][j] = __builtin_amdgcn_mfma_f32_16x16x32_bf16(af[i], uf[j], accu[i][j], 0, 0, 0);
                }
        }
        __syncthreads();   // vmcnt(0)+lgkmcnt(0)+barrier: next buffer staged, cur free
        cur ^= 1;
    }

    // epilogue: h = silu(g) * u
    #pragma unroll
    for (int i = 0; i < 4; i++)
        #pragma unroll
        for (int j = 0; j < 4; j++) {
            int nloc = wn * 64 + j * 16 + m15;
            size_t c = (size_t)nt * 128 + nloc;
            #pragma unroll
            for (int p = 0; p < 4; p++) {
                int mloc = wm * 64 + i * 16 + kq * 4 + p;
                int mrow = mt * 256 + mloc;
                if (mrow < Me) {
                    float g = accg[i][j][p], u = accu[i][j][p];
                    float sig = 1.0f / (1.0f + __expf(-g));
                    h[(size_t)(offe + mrow) * DFF + c] = (__bf16)(g * sig * u);
                }
            }
        }
}

// ---------------- k3: grouped GEMM down (MFMA), tile 128x128, dbuf prefetch ----------------
// 256 threads, 4 waves (2m x 2n); double-buffered LDS 64 KiB -> 2 blocks/CU.
__global__ __launch_bounds__(256, 2) void k3_down(
    const __bf16* __restrict__ h, const __bf16* __restrict__ dwb,
    const int* __restrict__ cnt, const int* __restrict__ off,
    const int* __restrict__ jobs, const int* __restrict__ njobs,
    __bf16* __restrict__ y) {
    int jt = blockIdx.x >> 3, nt = blockIdx.x & 7;    // nt: 0..7 (H/128)
    if (jt >= njobs[1]) return;
    int job = jobs[jt];
    int e = job >> 6, mt = job & 63;
    int Me = cnt[e], offe = off[e];

    __shared__ __bf16 As[2][128 * 64];   // 32 KB
    __shared__ __bf16 Bs[2][128 * 64];   // 32 KB

    int tid = threadIdx.x;
    int lane = tid & 63, w = tid >> 6;
    int wm = w >> 1, wn = w & 1;          // 2m x 2n waves

    const __bf16* asrc[4];
    const __bf16* bsrc[4];
    #pragma unroll
    for (int rr = 0; rr < 4; rr++) {
        int l = rr * 256 + tid;
        int row = l >> 3, sl = l & 7;
        int koff = (sl ^ (row & 7)) * 8;
        int gr = mt * 128 + row; if (gr >= Me) gr = Me - 1;
        asrc[rr] = h + (size_t)(offe + gr) * DFF + koff;
        bsrc[rr] = dwb + ((size_t)e * H + nt * 128 + row) * DFF + koff;
    }

    f32x4 acc[4][4] = {};
    int kq = lane >> 4, m15 = lane & 15;

    // prologue
    #pragma unroll
    for (int rr = 0; rr < 4; rr++) gload16(asrc[rr], &As[0][(rr * 256 + tid) * 8]);
    #pragma unroll
    for (int rr = 0; rr < 4; rr++) gload16(bsrc[rr], &Bs[0][(rr * 256 + tid) * 8]);
    __syncthreads();

    int cur = 0;
    for (int k0 = 0; k0 < DFF; k0 += 64) {
        if (k0 + 64 < DFF) {
            int nb = cur ^ 1, kn = k0 + 64;
            #pragma unroll
            for (int rr = 0; rr < 4; rr++) gload16(asrc[rr] + kn, &As[nb][(rr * 256 + tid) * 8]);
            #pragma unroll
            for (int rr = 0; rr < 4; rr++) gload16(bsrc[rr] + kn, &Bs[nb][(rr * 256 + tid) * 8]);
        }

        #pragma unroll
        for (int kc = 0; kc < 2; kc++) {
            bf16x8 af[4], bf[4];
            #pragma unroll
            for (int i = 0; i < 4; i++) {
                int row = wm * 64 + i * 16 + m15;
                int sl = (kc * 4 + kq) ^ (row & 7);
                af[i] = *(const bf16x8*)&As[cur][row * 64 + sl * 8];
            }
            #pragma unroll
            for (int j = 0; j < 4; j++) {
                int row = wn * 64 + j * 16 + m15;
                int sl = (kc * 4 + kq) ^ (row & 7);
                bf[j] = *(const bf16x8*)&Bs[cur][row * 64 + sl * 8];
            }
            #pragma unroll
            for (int i = 0; i < 4; i++)
                #pragma unroll
                for (int j = 0; j < 4; j++)
                    acc[i][j] = __builtin_amdgcn_mfma_f32_16x16x32_bf16(af[i], bf[j], acc[i][j], 0, 0, 0);
        }
        __syncthreads();
        cur ^= 1;
    }

    #pragma unroll
    for (int i = 0; i < 4; i++)
        #pragma unroll
        for (int j = 0; j < 4; j++) {
            int nglob = nt * 128 + wn * 64 + j * 16 + m15;
            #pragma unroll
            for (int p = 0; p < 4; p++) {
                int mloc = wm * 64 + i * 16 + kq * 4 + p;
                int mrow = mt * 128 + mloc;
                if (mrow < Me)
                    y[(size_t)(offe + mrow) * H + nglob] = (__bf16)acc[i][j][p];
            }
        }
}

// ---------------- gather: weighted top-2 combine -> out ----------------
__global__ __launch_bounds__(256) void k_gather(
    const __bf16* __restrict__ y, const int* __restrict__ se,
    const int* __restrict__ sp, const float* __restrict__ sw,
    const int* __restrict__ off, float* __restrict__ out) {
    int t = blockIdx.x;
    int r0 = off[se[2 * t]] + sp[2 * t];
    int r1 = off[se[2 * t + 1]] + sp[2 * t + 1];
    float w0 = sw[2 * t], w1 = sw[2 * t + 1];
    const bf16x4* y0 = (const bf16x4*)(y + (size_t)r0 * H);
    const bf16x4* y1 = (const bf16x4*)(y + (size_t)r1 * H);
    float4* o = (float4*)(out + (size_t)t * H);
    int c = threadIdx.x;
    bf16x4 a = y0[c], b = y1[c];
    float4 v;
    v.x = w0 * (float)a[0] + w1 * (float)b[0];
    v.y = w0 * (float)a[1] + w1 * (float)b[1];
    v.z = w0 * (float)a[2] + w1 * (float)b[2];
    v.w = w0 * (float)a[3] + w1 * (float)b[3];
    o[c] = v;
}

// ---------------- launch ----------------
extern "C" void kernel_launch(void* const* d_in, const int* in_sizes, int n_in,
                              void* d_out, int out_size, void* d_ws, size_t ws_size,
                              hipStream_t stream) {
    const float* x    = (const float*)d_in[0];
    const float* cent = (const float*)d_in[1];
    const float* gw   = (const float*)d_in[2];
    const float* uw   = (const float*)d_in[3];
    const float* dw   = (const float*)d_in[4];
    const float* bias = (const float*)d_in[5];
    float* out = (float*)d_out;

    // workspace layout (bytes)
    char* ws = (char*)d_ws;
    int*   cnt        = (int*)(ws + 0);
    int*   off        = (int*)(ws + 64);
    int*   se         = (int*)(ws + 128);              // 32 KB
    int*   sp         = (int*)(ws + 128 + 32768);      // 32 KB
    float* sw         = (float*)(ws + 128 + 65536);    // 32 KB
    int*   token_list = (int*)(ws + 128 + 98304);      // 128 KB
    int*   jobs2      = (int*)(ws + 229504);           // 40 ints
    int*   jobs3      = (int*)(ws + 229760);           // 72 ints
    int*   njobs      = (int*)(ws + 230400);           // 2 ints
    const size_t MB = 1u << 20;
    __bf16* gwb = (__bf16*)(ws + 1 * MB);              // 32 MB
    __bf16* uwb = (__bf16*)(ws + 1 * MB + 33554432);   // 32 MB
    __bf16* dwb = gwb;                                 // alias: after k2
    __bf16* y   = uwb;                                 // alias: uwb dead after k2
    __bf16* xb  = (__bf16*)(ws + 1 * MB + 67108864);   // 8 MB
    __bf16* h   = (__bf16*)(ws + 1 * MB + 75497472);   // 32 MB

    const int W4 = E * DFF * H / 4;
    const int X4 = T * H / 4;
    const int C3 = 2 * W4 + X4;

    k_conv3<<<(C3 + 255) / 256, 256, 0, stream>>>(gw, gwb, uw, uwb, x, xb, W4, X4);
    k1_affinity<<<T / 4, 256, 0, stream>>>(x, cent, bias, se, sw);
    k1b_partition<<<E, 256, 0, stream>>>(se, token_list, sp, cnt);
    k15_offsets<<<1, 64, 0, stream>>>(cnt, off, out + (size_t)T * H, jobs2, jobs3, njobs);
    k2_gateup<<<MAXJ2 * 16, 512, 0, stream>>>(xb, gwb, uwb, cnt, off, token_list, jobs2, njobs, h);
    k_conv<<<(W4 + 255) / 256, 256, 0, stream>>>(dw, dwb, W4);  // aliases gwb; after k2
    k3_down<<<MAXJ3 * 8, 256, 0, stream>>>(h, dwb, cnt, off, jobs3, njobs, y);  // y aliases uwb
    k_gather<<<T, 256, 0, stream>>>(y, se, sp, sw, off, out);
}

// Round 2
// 381.053 us; speedup vs baseline: 1.1170x; 1.1170x over previous
//
#include <hip/hip_runtime.h>
#include <math.h>

// Problem constants
constexpr int E = 8, H = 1024, DFF = 2048, T = 4096;
constexpr int TR = 8192;          // total routed rows = T * topk
constexpr int MAXJ = 72;          // max (expert, m-tile) jobs: 8192/128 + E

typedef __bf16 bf16x8 __attribute__((ext_vector_type(8)));
typedef __bf16 bf16x4 __attribute__((ext_vector_type(4)));
typedef float f32x4 __attribute__((ext_vector_type(4)));

__device__ __forceinline__ void gload16(const void* g, void* l) {
    __builtin_amdgcn_global_load_lds(
        (const __attribute__((address_space(1))) unsigned int*)g,
        (__attribute__((address_space(3))) unsigned int*)l, 16, 0, 0);
}

// ---------------- k0: fused conv3 (gw,uw,x -> bf16) + affinity/top-2 ----------------
// blocks [0,1024): affinity; blocks [1024, ...): fp32->bf16 conversion stream.
__global__ __launch_bounds__(256) void k0_fused(
    const float* __restrict__ x, const float* __restrict__ cent,
    const float* __restrict__ bias,
    int* __restrict__ se, float* __restrict__ sw,
    const float* __restrict__ gw, __bf16* __restrict__ gwb,
    const float* __restrict__ uw, __bf16* __restrict__ uwb,
    __bf16* __restrict__ xb, int w4, int x4) {
    __shared__ float cs[E * H];
    int tid = threadIdx.x;

    if (blockIdx.x >= 1024) {
        // conversion role
        int i = (blockIdx.x - 1024) * 256 + tid;
        const float* in; __bf16* out; int idx;
        if (i < w4) { in = gw; out = gwb; idx = i; }
        else if (i < 2 * w4) { in = uw; out = uwb; idx = i - w4; }
        else { idx = i - 2 * w4; if (idx >= x4) return; in = x; out = xb; }
        float4 v = ((const float4*)in)[idx];
        bf16x4 o = {(__bf16)v.x, (__bf16)v.y, (__bf16)v.z, (__bf16)v.w};
        ((bf16x4*)out)[idx] = o;
        return;
    }

    // affinity role
    for (int i = tid; i < E * H / 4; i += 256)
        ((float4*)cs)[i] = ((const float4*)cent)[i];
    __syncthreads();

    int wave = tid >> 6, lane = tid & 63;
    int t = blockIdx.x * 4 + wave;
    const float4* xr = (const float4*)(x + (size_t)t * H);
    float acc[E] = {};
    #pragma unroll
    for (int it = 0; it < 4; it++) {
        float4 xv = xr[lane + it * 64];
        #pragma unroll
        for (int e = 0; e < E; e++) {
            float4 cv = ((const float4*)(cs + e * H))[lane + it * 64];
            acc[e] = fmaf(xv.x, cv.x, acc[e]);
            acc[e] = fmaf(xv.y, cv.y, acc[e]);
            acc[e] = fmaf(xv.z, cv.z, acc[e]);
            acc[e] = fmaf(xv.w, cv.w, acc[e]);
        }
    }
    #pragma unroll
    for (int off = 32; off; off >>= 1)
        #pragma unroll
        for (int e = 0; e < E; e++) acc[e] += __shfl_down(acc[e], off);

    if (lane == 0) {
        float s[E];
        #pragma unroll
        for (int e = 0; e < E; e++)
            s[e] = 1.0f / (1.0f + expf(-acc[e])) + bias[e];
        int i0 = 0;
        for (int e = 1; e < E; e++) if (s[e] > s[i0]) i0 = e;
        int i1 = -1;
        for (int e = 0; e < E; e++) {
            if (e == i0) continue;
            if (i1 < 0 || s[e] > s[i1]) i1 = e;
        }
        float m = fmaxf(s[i0], s[i1]);
        float w0 = expf(s[i0] - m), w1 = expf(s[i1] - m);
        float inv = 1.0f / (w0 + w1);
        se[2 * t] = i0;     sw[2 * t] = w0 * inv;
        se[2 * t + 1] = i1; sw[2 * t + 1] = w1 * inv;
    }
}

// ---------------- k1b: per-expert partition via block scan (1024 threads) ----------------
__global__ __launch_bounds__(1024) void k1b_partition(
    const int* __restrict__ se, int* __restrict__ token_list,
    int* __restrict__ sp, int* __restrict__ cnt) {
    int e = blockIdx.x;
    int tid = threadIdx.x;
    int wave = tid >> 6, lane = tid & 63;
    __shared__ int wsum[16];
    int running = 0;
    for (int c0 = 0; c0 < 2 * T; c0 += 1024) {
        int i = c0 + tid;
        bool pred = (se[i] == e);
        unsigned long long mask = __ballot(pred);
        int pos_in_wave = __popcll(mask & ((1ull << lane) - 1ull));
        if (lane == 0) wsum[wave] = __popcll(mask);
        __syncthreads();
        int wbase = 0;
        #pragma unroll
        for (int w2 = 0; w2 < 16; w2++) {
            int v = wsum[w2];
            if (w2 < wave) wbase += v;
        }
        int total = 0;
        #pragma unroll
        for (int w2 = 0; w2 < 16; w2++) total += wsum[w2];
        if (pred) {
            int p = running + wbase + pos_in_wave;
            token_list[e * T + p] = i >> 1;
            sp[i] = p;
        }
        running += total;
        __syncthreads();
    }
    if (tid == 0) cnt[e] = running;
}

// ---------------- k1.5: offsets + counts output + job table ----------------
__global__ void k15_offsets(const int* __restrict__ cnt, int* __restrict__ off,
                            float* __restrict__ out_counts,
                            int* __restrict__ jobs, int* __restrict__ njobs) {
    if (threadIdx.x == 0) {
        int acc = 0, nj = 0;
        for (int e = 0; e < E; e++) {
            off[e] = acc; acc += cnt[e];
            int mts = (cnt[e] + 127) >> 7;
            for (int mt = 0; mt < mts; mt++) jobs[nj++] = e * 64 + mt;
        }
        njobs[0] = nj;
    }
    if (threadIdx.x < E) out_counts[threadIdx.x] = (float)cnt[threadIdx.x];
}

// ---------------- conv: fp32 -> bf16 (single tensor) ----------------
__global__ __launch_bounds__(256) void k_conv(const float* __restrict__ in,
                                              __bf16* __restrict__ out, int n4) {
    int i = blockIdx.x * 256 + threadIdx.x;
    if (i < n4) {
        float4 v = ((const float4*)in)[i];
        bf16x4 o = {(__bf16)v.x, (__bf16)v.y, (__bf16)v.z, (__bf16)v.w};
        ((bf16x4*)out)[i] = o;
    }
}

// ---------------- k2: grouped GEMM gate+up (MFMA), BK=64, tile 128x128 dual ----------------
// 4 waves 2x2; each wave owns a 64x64 region of BOTH gate and up accumulators.
// Single-buffered, 48 KB LDS -> 3 blocks/CU (implicit cross-block overlap).
__global__ __launch_bounds__(256, 2) void k2_gateup(
    const __bf16* __restrict__ xb, const __bf16* __restrict__ gwb,
    const __bf16* __restrict__ uwb, const int* __restrict__ cnt,
    const int* __restrict__ off, const int* __restrict__ token_list,
    const int* __restrict__ jobs, const int* __restrict__ njobs,
    __bf16* __restrict__ h) {
    int jt = blockIdx.x >> 4, nt = blockIdx.x & 15;   // nt: 0..15 (DFF/128)
    if (jt >= njobs[0]) return;
    int job = jobs[jt];
    int e = job >> 6, mt = job & 63;
    int Me = cnt[e], offe = off[e];

    __shared__ __bf16 As[128 * 64];   // 16 KB
    __shared__ __bf16 Bg[128 * 64];   // 16 KB
    __shared__ __bf16 Bu[128 * 64];   // 16 KB

    int tid = threadIdx.x;
    int lane = tid & 63, w = tid >> 6;
    int wm = w >> 1, wn = w & 1;

    // staging sources: LDS slot (row, l&7) receives global k-chunk (l&7)^(row&7)
    const __bf16* asrc[4];
    const __bf16 *bsg[4], *bsu[4];
    #pragma unroll
    for (int rr = 0; rr < 4; rr++) {
        int l = rr * 256 + tid;
        int row = l >> 3, sl = l & 7;
        int gr = mt * 128 + row; if (gr >= Me) gr = Me - 1;
        int tok = token_list[e * T + gr];
        asrc[rr] = xb + (size_t)tok * H + ((sl ^ (row & 7)) * 8);
        size_t base = ((size_t)e * DFF + nt * 128 + row) * H + ((sl ^ (row & 7)) * 8);
        bsg[rr] = gwb + base;
        bsu[rr] = uwb + base;
    }

    f32x4 accg[4][4] = {};
    f32x4 accu[4][4] = {};
    int kq = lane >> 4, m15 = lane & 15;

    for (int k0 = 0; k0 < H; k0 += 64) {
        #pragma unroll
        for (int rr = 0; rr < 4; rr++) {
            gload16(asrc[rr] + k0, &As[(rr * 256 + tid) * 8]);
            gload16(bsg[rr] + k0, &Bg[(rr * 256 + tid) * 8]);
            gload16(bsu[rr] + k0, &Bu[(rr * 256 + tid) * 8]);
        }
        __syncthreads();

        #pragma unroll
        for (int kc = 0; kc < 2; kc++) {
            bf16x8 af[4], gf[4], uf[4];
            #pragma unroll
            for (int i = 0; i < 4; i++) {
                int row = wm * 64 + i * 16 + m15;
                int sl = (kc * 4 + kq) ^ (row & 7);
                af[i] = *(const bf16x8*)&As[row * 64 + sl * 8];
            }
            #pragma unroll
            for (int j = 0; j < 4; j++) {
                int row = wn * 64 + j * 16 + m15;
                int sl = (kc * 4 + kq) ^ (row & 7);
                gf[j] = *(const bf16x8*)&Bg[row * 64 + sl * 8];
                uf[j] = *(const bf16x8*)&Bu[row * 64 + sl * 8];
            }
            #pragma unroll
            for (int i = 0; i < 4; i++)
                #pragma unroll
                for (int j = 0; j < 4; j++) {
                    accg[i][j] = __builtin_amdgcn_mfma_f32_16x16x32_bf16(af[i], gf[j], accg[i][j], 0, 0, 0);
                    accu[i][j] = __builtin_amdgcn_mfma_f32_16x16x32_bf16(af[i], uf[j], accu[i][j], 0, 0, 0);
                }
        }
        __syncthreads();
    }

    // epilogue: h = silu(g) * u
    #pragma unroll
    for (int i = 0; i < 4; i++)
        #pragma unroll
        for (int j = 0; j < 4; j++) {
            int nloc = wn * 64 + j * 16 + m15;
            size_t c = (size_t)nt * 128 + nloc;
            #pragma unroll
            for (int p = 0; p < 4; p++) {
                int mloc = wm * 64 + i * 16 + kq * 4 + p;
                int mrow = mt * 128 + mloc;
                if (mrow < Me) {
                    float g = accg[i][j][p], u = accu[i][j][p];
                    float sig = 1.0f / (1.0f + __expf(-g));
                    h[(size_t)(offe + mrow) * DFF + c] = (__bf16)(g * sig * u);
                }
            }
        }
}

// ---------------- k3: grouped GEMM down (MFMA), BK=64, tile 128x128 ----------------
// 256 threads, 4 waves (2m x 2n); single-buffered 32 KB LDS -> 4 blocks/CU
// (VGPR-limited), grid = jobs*8 for finer balance than the old 128x256/512t form.
__global__ __launch_bounds__(256, 2) void k3_down(
    const __bf16* __restrict__ h, const __bf16* __restrict__ dwb,
    const int* __restrict__ cnt, const int* __restrict__ off,
    const int* __restrict__ jobs, const int* __restrict__ njobs,
    __bf16* __restrict__ y) {
    int jt = blockIdx.x >> 3, nt = blockIdx.x & 7;    // nt: 0..7 (H/128)
    if (jt >= njobs[0]) return;
    int job = jobs[jt];
    int e = job >> 6, mt = job & 63;
    int Me = cnt[e], offe = off[e];

    __shared__ __bf16 As[128 * 64];   // 16 KB
    __shared__ __bf16 Bs[128 * 64];   // 16 KB

    int tid = threadIdx.x;
    int lane = tid & 63, w = tid >> 6;
    int wm = w >> 1, wn = w & 1;

    const __bf16* asrc[4];
    const __bf16* bsrc[4];
    #pragma unroll
    for (int rr = 0; rr < 4; rr++) {
        int l = rr * 256 + tid;
        int row = l >> 3, sl = l & 7;
        int koff = (sl ^ (row & 7)) * 8;
        int gr = mt * 128 + row; if (gr >= Me) gr = Me - 1;
        asrc[rr] = h + (size_t)(offe + gr) * DFF + koff;
        bsrc[rr] = dwb + ((size_t)e * H + nt * 128 + row) * DFF + koff;
    }

    f32x4 acc[4][4] = {};
    int kq = lane >> 4, m15 = lane & 15;

    for (int k0 = 0; k0 < DFF; k0 += 64) {
        #pragma unroll
        for (int rr = 0; rr < 4; rr++)
            gload16(asrc[rr] + k0, &As[(rr * 256 + tid) * 8]);
        #pragma unroll
        for (int rr = 0; rr < 4; rr++)
            gload16(bsrc[rr] + k0, &Bs[(rr * 256 + tid) * 8]);
        __syncthreads();

        #pragma unroll
        for (int kc = 0; kc < 2; kc++) {
            bf16x8 af[4], bf[4];
            #pragma unroll
            for (int i = 0; i < 4; i++) {
                int row = wm * 64 + i * 16 + m15;
                int sl = (kc * 4 + kq) ^ (row & 7);
                af[i] = *(const bf16x8*)&As[row * 64 + sl * 8];
            }
            #pragma unroll
            for (int j = 0; j < 4; j++) {
                int row = wn * 64 + j * 16 + m15;
                int sl = (kc * 4 + kq) ^ (row & 7);
                bf[j] = *(const bf16x8*)&Bs[row * 64 + sl * 8];
            }
            #pragma unroll
            for (int i = 0; i < 4; i++)
                #pragma unroll
                for (int j = 0; j < 4; j++)
                    acc[i][j] = __builtin_amdgcn_mfma_f32_16x16x32_bf16(af[i], bf[j], acc[i][j], 0, 0, 0);
        }
        __syncthreads();
    }

    #pragma unroll
    for (int i = 0; i < 4; i++)
        #pragma unroll
        for (int j = 0; j < 4; j++) {
            int nglob = nt * 128 + wn * 64 + j * 16 + m15;
            #pragma unroll
            for (int p = 0; p < 4; p++) {
                int mloc = wm * 64 + i * 16 + kq * 4 + p;
                int mrow = mt * 128 + mloc;
                if (mrow < Me)
                    y[(size_t)(offe + mrow) * H + nglob] = (__bf16)acc[i][j][p];
            }
        }
}

// ---------------- gather: weighted top-2 combine -> out ----------------
__global__ __launch_bounds__(256) void k_gather(
    const __bf16* __restrict__ y, const int* __restrict__ se,
    const int* __restrict__ sp, const float* __restrict__ sw,
    const int* __restrict__ off, float* __restrict__ out) {
    int t = blockIdx.x;
    int r0 = off[se[2 * t]] + sp[2 * t];
    int r1 = off[se[2 * t + 1]] + sp[2 * t + 1];
    float w0 = sw[2 * t], w1 = sw[2 * t + 1];
    const bf16x4* y0 = (const bf16x4*)(y + (size_t)r0 * H);
    const bf16x4* y1 = (const bf16x4*)(y + (size_t)r1 * H);
    float4* o = (float4*)(out + (size_t)t * H);
    int c = threadIdx.x;
    bf16x4 a = y0[c], b = y1[c];
    float4 v;
    v.x = w0 * (float)a[0] + w1 * (float)b[0];
    v.y = w0 * (float)a[1] + w1 * (float)b[1];
    v.z = w0 * (float)a[2] + w1 * (float)b[2];
    v.w = w0 * (float)a[3] + w1 * (float)b[3];
    o[c] = v;
}

// ---------------- launch ----------------
extern "C" void kernel_launch(void* const* d_in, const int* in_sizes, int n_in,
                              void* d_out, int out_size, void* d_ws, size_t ws_size,
                              hipStream_t stream) {
    const float* x    = (const float*)d_in[0];
    const float* cent = (const float*)d_in[1];
    const float* gw   = (const float*)d_in[2];
    const float* uw   = (const float*)d_in[3];
    const float* dw   = (const float*)d_in[4];
    const float* bias = (const float*)d_in[5];
    float* out = (float*)d_out;

    // workspace layout (bytes)
    char* ws = (char*)d_ws;
    int*   cnt        = (int*)(ws + 0);
    int*   off        = (int*)(ws + 64);
    int*   se         = (int*)(ws + 128);              // 32 KB
    int*   sp         = (int*)(ws + 128 + 32768);      // 32 KB
    float* sw         = (float*)(ws + 128 + 65536);    // 32 KB
    int*   token_list = (int*)(ws + 128 + 98304);      // 128 KB
    int*   jobs       = (int*)(ws + 229504);           // 80 ints
    int*   njobs      = (int*)(ws + 229824);           // 1 int
    const size_t MB = 1u << 20;
    __bf16* gwb = (__bf16*)(ws + 1 * MB);              // 32 MB
    __bf16* uwb = (__bf16*)(ws + 1 * MB + 33554432);   // 32 MB
    __bf16* dwb = gwb;                                 // alias: after k2
    __bf16* y   = uwb;                                 // alias: uwb dead after k2
    __bf16* xb  = (__bf16*)(ws + 1 * MB + 67108864);   // 8 MB
    __bf16* h   = (__bf16*)(ws + 1 * MB + 75497472);   // 32 MB

    const int W4 = E * DFF * H / 4;
    const int X4 = T * H / 4;
    const int C3 = 2 * W4 + X4;

    k0_fused<<<1024 + (C3 + 255) / 256, 256, 0, stream>>>(
        x, cent, bias, se, sw, gw, gwb, uw, uwb, xb, W4, X4);
    k1b_partition<<<E, 1024, 0, stream>>>(se, token_list, sp, cnt);
    k15_offsets<<<1, 64, 0, stream>>>(cnt, off, out + (size_t)T * H, jobs, njobs);
    k2_gateup<<<MAXJ * 16, 256, 0, stream>>>(xb, gwb, uwb, cnt, off, token_list, jobs, njobs, h);
    k_conv<<<(W4 + 255) / 256, 256, 0, stream>>>(dw, dwb, W4);  // aliases gwb; after k2
    k3_down<<<MAXJ * 8, 256, 0, stream>>>(h, dwb, cnt, off, jobs, njobs, y);  // y aliases uwb
    k_gather<<<T, 256, 0, stream>>>(y, se, sp, sw, off, out);
}